// Round 16
// baseline (36.048 us; speedup 1.0000x reference)
//
#include <hip/hip_runtime.h>
#include <stdint.h>

// Dynamic 3x3 softmax-weighted conv, reflect padding. Fused single pass,
// LDS DMA staging, XCD-chunked block swizzle, shuffle halo.
// Round 16: identical to round-11 best EXCEPT plain stores (no nontemporal
// hint) — isolating the nt-store variable that was never A/B'd.
// x: (4, 64, 256, 256) f32, kernel: (4, 9, 256, 256) f32, out: (4, 64, 256, 256) f32

constexpr int BATCH = 4;
constexpr int CHAN  = 64;
constexpr int HH    = 256;
constexpr int WW    = 256;
constexpr int CG    = 4;        // channels per block
constexpr int RPB   = 4;        // output rows per block (one wave per row)
constexpr int NROW  = RPB + 2;  // staged input rows per channel
constexpr int NWG   = (HH / RPB) * (CHAN / CG) * BATCH;  // 4096
constexpr int NXCD  = 8;
constexpr int CPX   = NWG / NXCD;                        // 512 (4096%8==0)

typedef float vf4 __attribute__((ext_vector_type(4)));
typedef const __attribute__((address_space(1))) void* gas_ptr;
typedef __attribute__((address_space(3))) void* las_ptr;

__global__ __launch_bounds__(256) void dynconv_kernel(
    const float* __restrict__ x,
    const float* __restrict__ ker,
    float* __restrict__ out)
{
    __shared__ float lds[CG][NROW][WW];   // 24 KiB

    // XCD-chunked bijective swizzle, hband fastest: each XCD sweeps
    // contiguous rows of one (cg,b) slice.
    const int id    = blockIdx.x;
    const int work  = (id & (NXCD - 1)) * CPX + (id >> 3);
    const int hband = work & 63;
    const int cg    = (work >> 6) & 15;
    const int b     = work >> 10;

    const int t  = threadIdx.x;
    const int rb = t >> 6;          // wave id = output row in band
    const int wq = t & 63;          // lane = float4 slot
    const int w0 = wq * 4;
    const int h0 = hband * RPB;
    const int h  = h0 + rb;

    const long cs = (long)HH * WW;
    const float* xb = x   + (((long)b * CHAN + cg * CG) * cs);
    float*       ob = out + (((long)b * CHAN + cg * CG) * cs);

    // ---- issue all 24 row-DMAs (6 per wave), zero VGPR held ----
    #pragma unroll
    for (int k = 0; k < (CG * NROW) / RPB; ++k) {
        const int idx  = k * RPB + rb;
        const int ch   = idx / NROW;
        const int slot = idx % NROW;
        int g = h0 - 1 + slot;
        g = (g < 0) ? 1 : ((g > HH - 1) ? HH - 2 : g);
        const float* gsrc = xb + (long)ch * cs + (long)g * WW + w0;
        __builtin_amdgcn_global_load_lds((gas_ptr)gsrc, (las_ptr)&lds[ch][slot][0], 16, 0, 0);
    }

    // ---- kernel loads + softmax overlap the DMA latency ----
    float kv[9][4];
    const long kbase = (((long)b * 9) * HH + h) * WW + w0;
    #pragma unroll
    for (int j = 0; j < 9; ++j) {
        const float4 v = *reinterpret_cast<const float4*>(ker + kbase + (long)j * HH * WW);
        kv[j][0] = v.x; kv[j][1] = v.y; kv[j][2] = v.z; kv[j][3] = v.w;
    }
    #pragma unroll
    for (int p = 0; p < 4; ++p) {
        float m = kv[0][p];
        #pragma unroll
        for (int j = 1; j < 9; ++j) m = fmaxf(m, kv[j][p]);
        float s = 0.f;
        #pragma unroll
        for (int j = 0; j < 9; ++j) { kv[j][p] = __expf(kv[j][p] - m); s += kv[j][p]; }
        const float inv = 1.0f / s;
        #pragma unroll
        for (int j = 0; j < 9; ++j) kv[j][p] *= inv;
    }

    __syncthreads();   // drains DMA, rows visible across waves

    // ---- conv from LDS; halo via cross-lane shuffle (no bank conflicts) ----
    #pragma unroll
    for (int i = 0; i < CG; ++i) {
        float acc0 = 0.f, acc1 = 0.f, acc2 = 0.f, acc3 = 0.f;
        #pragma unroll
        for (int r = 0; r < 3; ++r) {
            const float4 v = *reinterpret_cast<const float4*>(&lds[i][rb + r][w0]);
            float lft = __shfl_up(v.w, 1);
            if (wq == 0)  lft = v.y;     // reflect x[-1] -> x[1]
            float rgt = __shfl_down(v.x, 1);
            if (wq == 63) rgt = v.z;     // reflect x[256] -> x[254]
            const float vals[6] = { lft, v.x, v.y, v.z, v.w, rgt };
            #pragma unroll
            for (int dx = 0; dx < 3; ++dx) {
                const int j = r * 3 + dx;
                acc0 = fmaf(kv[j][0], vals[0 + dx], acc0);
                acc1 = fmaf(kv[j][1], vals[1 + dx], acc1);
                acc2 = fmaf(kv[j][2], vals[2 + dx], acc2);
                acc3 = fmaf(kv[j][3], vals[3 + dx], acc3);
            }
        }
        vf4 o; o.x = acc0; o.y = acc1; o.z = acc2; o.w = acc3;
        *reinterpret_cast<vf4*>(ob + (long)i * cs + (long)h * WW + w0) = o;  // plain store
    }
}

extern "C" void kernel_launch(void* const* d_in, const int* in_sizes, int n_in,
                              void* d_out, int out_size, void* d_ws, size_t ws_size,
                              hipStream_t stream) {
    const float* x   = (const float*)d_in[0];
    const float* ker = (const float*)d_in[1];
    float* out = (float*)d_out;

    dynconv_kernel<<<dim3(NWG), dim3(256), 0, stream>>>(x, ker, out);
}

// Round 17
// 33.519 us; speedup vs baseline: 1.0754x; 1.0754x over previous
//
#include <hip/hip_runtime.h>
#include <stdint.h>

// Dynamic 3x3 softmax-weighted conv, reflect padding. Fused single pass,
// LDS DMA staging, XCD-chunked block swizzle, shuffle halo, NT stores.
// Round 17: CG=8 — halves ker re-fetches per XCD-L2 sweep and softmax
// recompute; LDS 48 KiB.
// x: (4, 64, 256, 256) f32, kernel: (4, 9, 256, 256) f32, out: (4, 64, 256, 256) f32

constexpr int BATCH = 4;
constexpr int CHAN  = 64;
constexpr int HH    = 256;
constexpr int WW    = 256;
constexpr int CG    = 8;        // channels per block
constexpr int RPB   = 4;        // output rows per block (one wave per row)
constexpr int NROW  = RPB + 2;  // staged input rows per channel
constexpr int NWG   = (HH / RPB) * (CHAN / CG) * BATCH;  // 64*8*4 = 2048
constexpr int NXCD  = 8;
constexpr int CPX   = NWG / NXCD;                        // 256 (2048%8==0)

typedef float vf4 __attribute__((ext_vector_type(4)));
typedef const __attribute__((address_space(1))) void* gas_ptr;
typedef __attribute__((address_space(3))) void* las_ptr;

__global__ __launch_bounds__(256) void dynconv_kernel(
    const float* __restrict__ x,
    const float* __restrict__ ker,
    float* __restrict__ out)
{
    __shared__ float lds[CG][NROW][WW];   // 8*6*256*4B = 48 KiB

    // XCD-chunked bijective swizzle, hband fastest: each XCD sweeps
    // contiguous rows of one (cg,b) slice.
    const int id    = blockIdx.x;
    const int work  = (id & (NXCD - 1)) * CPX + (id >> 3);
    const int hband = work & 63;
    const int cg    = (work >> 6) & 7;
    const int b     = work >> 9;

    const int t  = threadIdx.x;
    const int rb = t >> 6;          // wave id = output row in band
    const int wq = t & 63;          // lane = float4 slot
    const int w0 = wq * 4;
    const int h0 = hband * RPB;
    const int h  = h0 + rb;

    const long cs = (long)HH * WW;
    const float* xb = x   + (((long)b * CHAN + cg * CG) * cs);
    float*       ob = out + (((long)b * CHAN + cg * CG) * cs);

    // ---- issue all 48 row-DMAs (12 per wave), zero VGPR held ----
    #pragma unroll
    for (int k = 0; k < (CG * NROW) / RPB; ++k) {   // 12 iterations
        const int idx  = k * RPB + rb;              // 0..47, disjoint across waves
        const int ch   = idx / NROW;
        const int slot = idx % NROW;
        int g = h0 - 1 + slot;
        g = (g < 0) ? 1 : ((g > HH - 1) ? HH - 2 : g);
        const float* gsrc = xb + (long)ch * cs + (long)g * WW + w0;
        __builtin_amdgcn_global_load_lds((gas_ptr)gsrc, (las_ptr)&lds[ch][slot][0], 16, 0, 0);
    }

    // ---- kernel loads + softmax overlap the DMA latency ----
    float kv[9][4];
    const long kbase = (((long)b * 9) * HH + h) * WW + w0;
    #pragma unroll
    for (int j = 0; j < 9; ++j) {
        const float4 v = *reinterpret_cast<const float4*>(ker + kbase + (long)j * HH * WW);
        kv[j][0] = v.x; kv[j][1] = v.y; kv[j][2] = v.z; kv[j][3] = v.w;
    }
    #pragma unroll
    for (int p = 0; p < 4; ++p) {
        float m = kv[0][p];
        #pragma unroll
        for (int j = 1; j < 9; ++j) m = fmaxf(m, kv[j][p]);
        float s = 0.f;
        #pragma unroll
        for (int j = 0; j < 9; ++j) { kv[j][p] = __expf(kv[j][p] - m); s += kv[j][p]; }
        const float inv = 1.0f / s;
        #pragma unroll
        for (int j = 0; j < 9; ++j) kv[j][p] *= inv;
    }

    __syncthreads();   // drains DMA, rows visible across waves

    // ---- conv from LDS; halo via cross-lane shuffle (no bank conflicts) ----
    #pragma unroll
    for (int i = 0; i < CG; ++i) {
        float acc0 = 0.f, acc1 = 0.f, acc2 = 0.f, acc3 = 0.f;
        #pragma unroll
        for (int r = 0; r < 3; ++r) {
            const float4 v = *reinterpret_cast<const float4*>(&lds[i][rb + r][w0]);
            float lft = __shfl_up(v.w, 1);
            if (wq == 0)  lft = v.y;     // reflect x[-1] -> x[1]
            float rgt = __shfl_down(v.x, 1);
            if (wq == 63) rgt = v.z;     // reflect x[256] -> x[254]
            const float vals[6] = { lft, v.x, v.y, v.z, v.w, rgt };
            #pragma unroll
            for (int dx = 0; dx < 3; ++dx) {
                const int j = r * 3 + dx;
                acc0 = fmaf(kv[j][0], vals[0 + dx], acc0);
                acc1 = fmaf(kv[j][1], vals[1 + dx], acc1);
                acc2 = fmaf(kv[j][2], vals[2 + dx], acc2);
                acc3 = fmaf(kv[j][3], vals[3 + dx], acc3);
            }
        }
        vf4 o; o.x = acc0; o.y = acc1; o.z = acc2; o.w = acc3;
        __builtin_nontemporal_store(o,
            reinterpret_cast<vf4*>(ob + (long)i * cs + (long)h * WW + w0));
    }
}

extern "C" void kernel_launch(void* const* d_in, const int* in_sizes, int n_in,
                              void* d_out, int out_size, void* d_ws, size_t ws_size,
                              hipStream_t stream) {
    const float* x   = (const float*)d_in[0];
    const float* ker = (const float*)d_in[1];
    float* out = (float*)d_out;

    dynconv_kernel<<<dim3(NWG), dim3(256), 0, stream>>>(x, ker, out);
}

// Round 18
// 27.997 us; speedup vs baseline: 1.2876x; 1.1973x over previous
//
#include <hip/hip_runtime.h>
#include <stdint.h>

// Dynamic 3x3 softmax-weighted conv, reflect padding. BEST CONFIG (round 11):
// fused single pass, LDS DMA staging (24 KiB), XCD-chunked bijective block
// swizzle, cross-lane shuffle halo (0 bank conflicts), nontemporal stores
// (protects per-XCD L2 from write-allocate eviction — r16 proved -23% without).
// CG=4 (r17 proved CG=8 worse: LDS doubles, occupancy halves, FETCH rises).
// x: (4, 64, 256, 256) f32, kernel: (4, 9, 256, 256) f32, out: (4, 64, 256, 256) f32

constexpr int BATCH = 4;
constexpr int CHAN  = 64;
constexpr int HH    = 256;
constexpr int WW    = 256;
constexpr int CG    = 4;        // channels per block
constexpr int RPB   = 4;        // output rows per block (one wave per row)
constexpr int NROW  = RPB + 2;  // staged input rows per channel
constexpr int NWG   = (HH / RPB) * (CHAN / CG) * BATCH;  // 4096
constexpr int NXCD  = 8;
constexpr int CPX   = NWG / NXCD;                        // 512 (4096%8==0)

typedef float vf4 __attribute__((ext_vector_type(4)));
typedef const __attribute__((address_space(1))) void* gas_ptr;
typedef __attribute__((address_space(3))) void* las_ptr;

__global__ __launch_bounds__(256) void dynconv_kernel(
    const float* __restrict__ x,
    const float* __restrict__ ker,
    float* __restrict__ out)
{
    __shared__ float lds[CG][NROW][WW];   // 24 KiB

    // XCD-chunked bijective swizzle, hband fastest: each XCD sweeps
    // contiguous rows of one (cg,b) slice.
    const int id    = blockIdx.x;
    const int work  = (id & (NXCD - 1)) * CPX + (id >> 3);
    const int hband = work & 63;
    const int cg    = (work >> 6) & 15;
    const int b     = work >> 10;

    const int t  = threadIdx.x;
    const int rb = t >> 6;          // wave id = output row in band
    const int wq = t & 63;          // lane = float4 slot
    const int w0 = wq * 4;
    const int h0 = hband * RPB;
    const int h  = h0 + rb;

    const long cs = (long)HH * WW;
    const float* xb = x   + (((long)b * CHAN + cg * CG) * cs);
    float*       ob = out + (((long)b * CHAN + cg * CG) * cs);

    // ---- issue all 24 row-DMAs (6 per wave), zero VGPR held ----
    #pragma unroll
    for (int k = 0; k < (CG * NROW) / RPB; ++k) {
        const int idx  = k * RPB + rb;
        const int ch   = idx / NROW;
        const int slot = idx % NROW;
        int g = h0 - 1 + slot;
        g = (g < 0) ? 1 : ((g > HH - 1) ? HH - 2 : g);
        const float* gsrc = xb + (long)ch * cs + (long)g * WW + w0;
        __builtin_amdgcn_global_load_lds((gas_ptr)gsrc, (las_ptr)&lds[ch][slot][0], 16, 0, 0);
    }

    // ---- kernel loads + softmax overlap the DMA latency ----
    float kv[9][4];
    const long kbase = (((long)b * 9) * HH + h) * WW + w0;
    #pragma unroll
    for (int j = 0; j < 9; ++j) {
        const float4 v = *reinterpret_cast<const float4*>(ker + kbase + (long)j * HH * WW);
        kv[j][0] = v.x; kv[j][1] = v.y; kv[j][2] = v.z; kv[j][3] = v.w;
    }
    #pragma unroll
    for (int p = 0; p < 4; ++p) {
        float m = kv[0][p];
        #pragma unroll
        for (int j = 1; j < 9; ++j) m = fmaxf(m, kv[j][p]);
        float s = 0.f;
        #pragma unroll
        for (int j = 0; j < 9; ++j) { kv[j][p] = __expf(kv[j][p] - m); s += kv[j][p]; }
        const float inv = 1.0f / s;
        #pragma unroll
        for (int j = 0; j < 9; ++j) kv[j][p] *= inv;
    }

    __syncthreads();   // drains DMA, rows visible across waves

    // ---- conv from LDS; halo via cross-lane shuffle (no bank conflicts) ----
    #pragma unroll
    for (int i = 0; i < CG; ++i) {
        float acc0 = 0.f, acc1 = 0.f, acc2 = 0.f, acc3 = 0.f;
        #pragma unroll
        for (int r = 0; r < 3; ++r) {
            const float4 v = *reinterpret_cast<const float4*>(&lds[i][rb + r][w0]);
            float lft = __shfl_up(v.w, 1);
            if (wq == 0)  lft = v.y;     // reflect x[-1] -> x[1]
            float rgt = __shfl_down(v.x, 1);
            if (wq == 63) rgt = v.z;     // reflect x[256] -> x[254]
            const float vals[6] = { lft, v.x, v.y, v.z, v.w, rgt };
            #pragma unroll
            for (int dx = 0; dx < 3; ++dx) {
                const int j = r * 3 + dx;
                acc0 = fmaf(kv[j][0], vals[0 + dx], acc0);
                acc1 = fmaf(kv[j][1], vals[1 + dx], acc1);
                acc2 = fmaf(kv[j][2], vals[2 + dx], acc2);
                acc3 = fmaf(kv[j][3], vals[3 + dx], acc3);
            }
        }
        vf4 o; o.x = acc0; o.y = acc1; o.z = acc2; o.w = acc3;
        __builtin_nontemporal_store(o,
            reinterpret_cast<vf4*>(ob + (long)i * cs + (long)h * WW + w0));
    }
}

extern "C" void kernel_launch(void* const* d_in, const int* in_sizes, int n_in,
                              void* d_out, int out_size, void* d_ws, size_t ws_size,
                              hipStream_t stream) {
    const float* x   = (const float*)d_in[0];
    const float* ker = (const float*)d_in[1];
    float* out = (float*)d_out;

    dynconv_kernel<<<dim3(NWG), dim3(256), 0, stream>>>(x, ker, out);
}